// Round 8
// baseline (3166.886 us; speedup 1.0000x reference)
//
#include <hip/hip_runtime.h>
#include <math.h>

#define IN_DIM 1024
#define H2     2048
#define HID    1024
#define NEXP   64
#define TOPK   8
#define RISK_TH 1.5e-4f

typedef short  v8s __attribute__((ext_vector_type(8)));   // 8 bf16 (MFMA A/B frag)
typedef float  v4f __attribute__((ext_vector_type(4)));   // 4 f32  (MFMA C/D frag)

// split fp32 -> bf16 hi + bf16 lo (truncation; combined 16-bit mantissa, rel err ~2^-16)
__device__ __forceinline__ void bf16_split(float f, ushort& h, ushort& l) {
    unsigned uh = __float_as_uint(f) & 0xffff0000u;
    h = (ushort)(uh >> 16);
    float r = f - __uint_as_float(uh);
    l = (ushort)(__float_as_uint(r) >> 16);
}

// async global->LDS, 16B per lane. LDS dest is wave-uniform base + lane*16.
__device__ __forceinline__ void gload16(const ushort* g, ushort* l) {
    __builtin_amdgcn_global_load_lds(
        (const __attribute__((address_space(1))) void*)g,
        (__attribute__((address_space(3))) void*)l, 16, 0, 0);
}

// ---------------- weight split+transpose: W[K,N] f32 -> WT_hi/lo[N,K] bf16 ----------------
__global__ __launch_bounds__(256)
void split_w_kernel(const float* __restrict__ W, ushort* __restrict__ hiT,
                    ushort* __restrict__ loT, int K, int N)
{
    __shared__ float T[64][65];
    const int k0 = blockIdx.y * 64, n0 = blockIdx.x * 64;
    const int t = threadIdx.x;
#pragma unroll
    for (int j = 0; j < 4; ++j) {
        int idx = t + j * 256;
        int row = idx >> 4;            // k-local 0..63
        int c4  = (idx & 15) * 4;      // n-local
        float4 f = *(const float4*)(W + (long)(k0 + row) * N + n0 + c4);
        T[row][c4 + 0] = f.x; T[row][c4 + 1] = f.y;
        T[row][c4 + 2] = f.z; T[row][c4 + 3] = f.w;
    }
    __syncthreads();
#pragma unroll
    for (int j = 0; j < 4; ++j) {
        int idx = t + j * 256;
        int nn = idx >> 4;             // n-local 0..63
        int kq = (idx & 15) * 4;       // k-local
        ushort4 h4, l4;
        bf16_split(T[kq + 0][nn], h4.x, l4.x);
        bf16_split(T[kq + 1][nn], h4.y, l4.y);
        bf16_split(T[kq + 2][nn], h4.z, l4.z);
        bf16_split(T[kq + 3][nn], h4.w, l4.w);
        long o = (long)(n0 + nn) * K + k0 + kq;
        *(ushort4*)(hiT + o) = h4;
        *(ushort4*)(loT + o) = l4;
    }
}

// ---------------- x split: fp32 [M,K] -> hi/lo bf16 planes [M,K] ----------------
__global__ __launch_bounds__(256)
void split_x_kernel(const float* __restrict__ X, ushort* __restrict__ hi,
                    ushort* __restrict__ lo)
{
    long i = ((long)blockIdx.x * 256 + threadIdx.x) * 4;
    float4 f = *(const float4*)(X + i);
    ushort4 h4, l4;
    bf16_split(f.x, h4.x, l4.x);
    bf16_split(f.y, h4.y, l4.y);
    bf16_split(f.z, h4.z, l4.z);
    bf16_split(f.w, h4.w, l4.w);
    *(ushort4*)(hi + i) = h4;
    *(ushort4*)(lo + i) = l4;
}

// ---------------- big GEMM: 256xBN bf16x3 MFMA, counted-vmcnt (T4) pipeline ----------------
// A planes [M,K] bf16 (hi/lo), B planes [N,K] bf16 (hi/lo). C = relu(A@B + bias),
// written as fp32 OR as hi/lo planes (for the next layer's A).
// BM=256, BN=NWN*64, BK=32, 8 waves. LDS: 2 buffers x {Ahi,Alo,Bhi,Blo}[rows][32],
// global_load_lds, pre-swizzled per-lane global addresses (bank-conflict-free,
// SQ_LDS_BANK_CONFLICT=0).
// SCHEDULE (rounds 5-7 post-mortem): per-CU staging rate was pinned at 9.8 B/cyc
// across ALL intra-tile schedules (fenced / unfenced / rhythm-barriered all
// 177-182us) -> the limiter is the DMA queue draining to 0 at every tile's
// vmcnt(0) (strict double-buffer = max 1-tile prefetch). m201 sustains ~19 B/cyc
// on the SAME tile/LDS/DMA path via counted vmcnt (T4; m218: counted-vs-drain0
// = +38%@4k). Fix: the zigzag's last read of buf(t) is R2 (A1 frags), so after
// R2 we drain lgkmcnt(0)+barrier (all reads of buf(t) provably complete chip-wide
// -> no WAR race), issue G(t+2) INTO buf(t) before P2/P3, and the end-of-tile
// wait becomes counted vmcnt(8) (G(t+1) landed, G(t+2) stays in flight). Queue
// never empties: 8-16 loads outstanding in steady state, prefetch window ~1.5
// tiles. 2 barriers/tile.
// Zigzag quadrants (0,0)->(0,1)->(1,1)->(1,0): LDS reads at 24KB/wave/tile min.
// XCD-aware bijective block swizzle. MFMA order per acc: al*bh, ah*bl, ah*bh
// over ascending k-tiles -> bit-identical output.
template<int MI, int NWN>
__global__ __launch_bounds__(512, 2)
void gemm8p_kernel(const ushort* __restrict__ gAhi, const ushort* __restrict__ gAlo,
                   const ushort* __restrict__ gBhi, const ushort* __restrict__ gBlo,
                   const float* __restrict__ bias,
                   float* __restrict__ Cf32, ushort* __restrict__ Chi,
                   ushort* __restrict__ Clo, int N, int K)
{
    static_assert(MI == 2 * NWN, "wave grid must tile 256 rows");
    constexpr int BN    = NWN * 64;
    constexpr int ATILE = 256 * 32;          // ushorts per A plane tile (16KB)
    constexpr int BTILE = BN * 32;
    constexpr int BUFU  = 2 * ATILE + 2 * BTILE;
    constexpr int MH    = MI / 2;            // frag-rows per quadrant
    __shared__ __align__(16) ushort lds[2 * BUFU];

    const int tid  = threadIdx.x;
    const int w    = tid >> 6;
    const int lane = tid & 63;
    const int wm   = w / NWN;
    const int wn   = w % NWN;
    const int q    = lane >> 4;
    const int l15  = lane & 15;

    // XCD-aware bijective swizzle (gridDim.x == 8 here).
    const int nwg = (int)(gridDim.x * gridDim.y);
    const int h   = (int)(blockIdx.y * gridDim.x + blockIdx.x);
    const int l   = (h & 7) * (nwg >> 3) + (h >> 3);
    const long bm = (long)(l >> 3) * 256;
    const long bn = (long)(l & 7) * BN;

    const int  e   = lane >> 2;                               // row within slab
    const int  s8  = (((lane & 3) ^ ((lane >> 3) & 3)) * 8);  // swizzled slot (ushorts)
    const int  fragUS = ((q ^ ((l15 >> 1) & 3)) * 8);

    const int NT = K >> 5;

    // per-wave gload16 per tile: A=4, B=4 (BN=256) or 2 (BN=128)
    auto stageA = [&](int ktv, ushort* nb) {
        const long gr = bm + w * 16 + e;
        gload16(gAhi + gr * K + ktv + s8,         nb + w * 512);
        gload16(gAhi + (gr + 128) * K + ktv + s8, nb + 128 * 32 + w * 512);
        gload16(gAlo + gr * K + ktv + s8,         nb + ATILE + w * 512);
        gload16(gAlo + (gr + 128) * K + ktv + s8, nb + ATILE + 128 * 32 + w * 512);
    };
    auto stageB = [&](int ktv, ushort* nb) {
        const long gr = bn + w * 16 + e;
        gload16(gBhi + gr * K + ktv + s8,         nb + 2 * ATILE + w * 512);
        gload16(gBlo + gr * K + ktv + s8,         nb + 2 * ATILE + BTILE + w * 512);
        if constexpr (BN == 256) {
            gload16(gBhi + (gr + 128) * K + ktv + s8, nb + 2 * ATILE + 128 * 32 + w * 512);
            gload16(gBlo + (gr + 128) * K + ktv + s8, nb + 2 * ATILE + BTILE + 128 * 32 + w * 512);
        }
    };

    v4f acc[MI][4];
#pragma unroll
    for (int mi = 0; mi < MI; ++mi)
#pragma unroll
        for (int ni = 0; ni < 4; ++ni)
            acc[mi][ni] = (v4f){0.f, 0.f, 0.f, 0.f};

    // ---- prologue: issue G(0) and G(1); wait only for G(0) (counted) ----
    stageA(0, lds);
    stageB(0, lds);
    if (NT > 1) {
        stageA(32, lds + BUFU);
        stageB(32, lds + BUFU);
        if constexpr (BN == 256) asm volatile("s_waitcnt vmcnt(8)" ::: "memory");
        else                     asm volatile("s_waitcnt vmcnt(6)" ::: "memory");
    } else {
        asm volatile("s_waitcnt vmcnt(0)" ::: "memory");
    }
    __builtin_amdgcn_s_barrier();
    __builtin_amdgcn_sched_barrier(0);

    // ---- main loop: one K-tile per iteration, 2 barriers, queue never empty ----
    for (int t = 0; t < NT; ++t) {
        const ushort* cA = lds + (t & 1) * BUFU;
        const ushort* cB = cA + 2 * ATILE;
        ushort* rb = lds + (t & 1) * BUFU;      // G(t+2) re-stages this buffer
        const bool issue2 = (t + 2 < NT);
        const int  kt2 = (t + 2) << 5;

        v8s ah[MH], al[MH];          // current mh-half A frags (reloaded at R2)
        v8s bh0[2], bl0[2];          // nh=0 B frags (held through P3)
        v8s bh1[2], bl1[2];          // nh=1 B frags (used P1/P2)

        // ---- R0/R1: A0, B0, B1 frag reads (compiler inserts counted lgkmcnt) ----
#pragma unroll
        for (int i = 0; i < MH; ++i) {
            int r = wm * (MI * 16) + i * 16 + l15;
            const ushort* pA = cA + r * 32 + fragUS;
            ah[i] = *(const v8s*)pA;
            al[i] = *(const v8s*)(pA + ATILE);
        }
#pragma unroll
        for (int j = 0; j < 2; ++j) {
            int r = wn * 64 + j * 16 + l15;
            const ushort* pB = cB + r * 32 + fragUS;
            bh0[j] = *(const v8s*)pB;
            bl0[j] = *(const v8s*)(pB + BTILE);
        }
#pragma unroll
        for (int j = 0; j < 2; ++j) {
            int r = wn * 64 + (2 + j) * 16 + l15;
            const ushort* pB = cB + r * 32 + fragUS;
            bh1[j] = *(const v8s*)pB;
            bl1[j] = *(const v8s*)(pB + BTILE);
        }

        // ---- P0: quadrant (0,0) ----
        __builtin_amdgcn_s_setprio(1);
#pragma unroll
        for (int i = 0; i < MH; ++i)
#pragma unroll
            for (int j = 0; j < 2; ++j) {
                v4f c = acc[i][j];
                c = __builtin_amdgcn_mfma_f32_16x16x32_bf16(al[i], bh0[j], c, 0, 0, 0);
                c = __builtin_amdgcn_mfma_f32_16x16x32_bf16(ah[i], bl0[j], c, 0, 0, 0);
                c = __builtin_amdgcn_mfma_f32_16x16x32_bf16(ah[i], bh0[j], c, 0, 0, 0);
                acc[i][j] = c;
            }
        __builtin_amdgcn_s_setprio(0);

        // ---- P1: quadrant (0,1) — reuse A0, use B1 ----
        __builtin_amdgcn_s_setprio(1);
#pragma unroll
        for (int i = 0; i < MH; ++i)
#pragma unroll
            for (int j = 0; j < 2; ++j) {
                v4f c = acc[i][2 + j];
                c = __builtin_amdgcn_mfma_f32_16x16x32_bf16(al[i], bh1[j], c, 0, 0, 0);
                c = __builtin_amdgcn_mfma_f32_16x16x32_bf16(ah[i], bl1[j], c, 0, 0, 0);
                c = __builtin_amdgcn_mfma_f32_16x16x32_bf16(ah[i], bh1[j], c, 0, 0, 0);
                acc[i][2 + j] = c;
            }
        __builtin_amdgcn_s_setprio(0);

        // ---- R2: A1 frag reads — the LAST reads of buf(t) ----
#pragma unroll
        for (int i = 0; i < MH; ++i) {
            int r = wm * (MI * 16) + (MH + i) * 16 + l15;
            const ushort* pA = cA + r * 32 + fragUS;
            ah[i] = *(const v8s*)pA;
            al[i] = *(const v8s*)(pA + ATILE);
        }
        // drain this wave's reads, then barrier: ALL waves' reads of buf(t) are
        // complete chip-wide -> safe to DMA-overwrite buf(t) with G(t+2).
        asm volatile("s_waitcnt lgkmcnt(0)" ::: "memory");
        __builtin_amdgcn_sched_barrier(0);
        __builtin_amdgcn_s_barrier();
        __builtin_amdgcn_sched_barrier(0);
        if (issue2) {
            stageA(kt2, rb);
            stageB(kt2, rb);
        }
        __builtin_amdgcn_sched_barrier(0);

        // ---- P2: quadrant (1,1); P3: quadrant (1,0) — G(t+2) flies underneath ----
        __builtin_amdgcn_s_setprio(1);
#pragma unroll
        for (int i = 0; i < MH; ++i)
#pragma unroll
            for (int j = 0; j < 2; ++j) {
                v4f c = acc[MH + i][2 + j];
                c = __builtin_amdgcn_mfma_f32_16x16x32_bf16(al[i], bh1[j], c, 0, 0, 0);
                c = __builtin_amdgcn_mfma_f32_16x16x32_bf16(ah[i], bl1[j], c, 0, 0, 0);
                c = __builtin_amdgcn_mfma_f32_16x16x32_bf16(ah[i], bh1[j], c, 0, 0, 0);
                acc[MH + i][2 + j] = c;
            }
#pragma unroll
        for (int i = 0; i < MH; ++i)
#pragma unroll
            for (int j = 0; j < 2; ++j) {
                v4f c = acc[MH + i][j];
                c = __builtin_amdgcn_mfma_f32_16x16x32_bf16(al[i], bh0[j], c, 0, 0, 0);
                c = __builtin_amdgcn_mfma_f32_16x16x32_bf16(ah[i], bl0[j], c, 0, 0, 0);
                c = __builtin_amdgcn_mfma_f32_16x16x32_bf16(ah[i], bh0[j], c, 0, 0, 0);
                acc[MH + i][j] = c;
            }
        __builtin_amdgcn_s_setprio(0);

        // ---- end of tile: counted wait — G(t+1) landed, G(t+2) stays in flight ----
        if (t + 1 < NT) {
            if (issue2) {
                if constexpr (BN == 256) asm volatile("s_waitcnt vmcnt(8)" ::: "memory");
                else                     asm volatile("s_waitcnt vmcnt(6)" ::: "memory");
            } else {
                asm volatile("s_waitcnt vmcnt(0)" ::: "memory");
            }
            __builtin_amdgcn_sched_barrier(0);
            __builtin_amdgcn_s_barrier();
            __builtin_amdgcn_sched_barrier(0);
        }
    }

    // ---- epilogue: bias + relu; fp32 or hi/lo-plane output ----
#pragma unroll
    for (int ni = 0; ni < 4; ++ni) {
        int col = (int)(bn + wn * 64 + ni * 16 + l15);
        float bv = bias[col];
#pragma unroll
        for (int mi = 0; mi < MI; ++mi) {
            long row0 = bm + wm * (MI * 16) + mi * 16 + q * 4;
#pragma unroll
            for (int r = 0; r < 4; ++r) {
                float v = fmaxf(acc[mi][ni][r] + bv, 0.f);
                long o = (row0 + r) * (long)N + col;
                if (Cf32) {
                    Cf32[o] = v;
                } else {
                    ushort hh, ll;
                    bf16_split(v, hh, ll);
                    Chi[o] = hh;
                    Clo[o] = ll;
                }
            }
        }
    }
}

// ---------------- small GEMM (N=64): C = A@B + bias, fp32 ----------------
#define SBM 64
#define SBK 32
#define SLDA 68

__global__ __launch_bounds__(256, 2)
void small_gemm_kernel(const float* __restrict__ A, const float* __restrict__ B,
                       const float* __restrict__ bias, float* __restrict__ C,
                       int K)
{
    __shared__ __align__(16) float Hs[SBK][SLDA];
    __shared__ __align__(16) float Ws[SBK][NEXP];
    const int tid = threadIdx.x;
    const int tx = tid & 15;
    const int ty = tid >> 4;
    const long bm = (long)blockIdx.x * SBM;
    const float* Ab = A + bm * K;

    float acc[4][4];
#pragma unroll
    for (int i = 0; i < 4; ++i)
#pragma unroll
        for (int j = 0; j < 4; ++j) acc[i][j] = 0.f;

    float4 aR[2], bR[2];
#pragma unroll
    for (int j = 0; j < 2; ++j) {
        int idx = tid + (j << 8);
        int ar = idx >> 3, ac = (idx & 7) << 2;
        aR[j] = *(const float4*)(Ab + (long)ar * K + ac);
        int br = idx >> 4, bc = (idx & 15) << 2;
        bR[j] = *(const float4*)(B + (long)br * NEXP + bc);
    }

    int kt = 0;
    for (;;) {
#pragma unroll
        for (int j = 0; j < 2; ++j) {
            int idx = tid + (j << 8);
            int ar = idx >> 3, ac = (idx & 7) << 2;
            Hs[ac + 0][ar] = aR[j].x;
            Hs[ac + 1][ar] = aR[j].y;
            Hs[ac + 2][ar] = aR[j].z;
            Hs[ac + 3][ar] = aR[j].w;
            int br = idx >> 4, bc = (idx & 15) << 2;
            *(float4*)&Ws[br][bc] = bR[j];
        }
        __syncthreads();

        kt += SBK;
        if (kt < K) {
#pragma unroll
            for (int j = 0; j < 2; ++j) {
                int idx = tid + (j << 8);
                int ar = idx >> 3, ac = (idx & 7) << 2;
                aR[j] = *(const float4*)(Ab + (long)ar * K + kt + ac);
                int br = idx >> 4, bc = (idx & 15) << 2;
                bR[j] = *(const float4*)(B + (long)(kt + br) * NEXP + bc);
            }
        }

#pragma unroll
        for (int k = 0; k < SBK; ++k) {
            float a[4], b[4];
            *(float4*)&a[0] = *(const float4*)&Hs[k][ty * 4];
            *(float4*)&b[0] = *(const float4*)&Ws[k][tx * 4];
#pragma unroll
            for (int i = 0; i < 4; ++i)
#pragma unroll
                for (int j = 0; j < 4; ++j)
                    acc[i][j] = fmaf(a[i], b[j], acc[i][j]);
        }
        __syncthreads();
        if (kt >= K) break;
    }

    float bv[4];
#pragma unroll
    for (int j = 0; j < 4; ++j) bv[j] = bias[tx * 4 + j];
#pragma unroll
    for (int i = 0; i < 4; ++i) {
        long row = bm + ty * 4 + i;
        float o[4];
#pragma unroll
        for (int j = 0; j < 4; ++j) o[j] = acc[i][j] + bv[j];
        *(float4*)(C + row * NEXP + tx * 4) = *(const float4*)&o[0];
    }
}

// ---------------- router (fp32) + risky-row detection ----------------
__global__ __launch_bounds__(256)
void router_kernel(const float* __restrict__ logits, const float* __restrict__ nlog,
                   const float* __restrict__ noise, float* __restrict__ rout,
                   float* __restrict__ idx_out, int rows, int rowBase,
                   int* __restrict__ ctrl, int* __restrict__ list, int maxr)
{
    const int wave = threadIdx.x >> 6;
    const int lane = threadIdx.x & 63;
    const long row = (long)blockIdx.x * 4 + wave;
    if (row >= rows) return;

    float lg = logits[row * NEXP + lane];
    float nl = nlog[row * NEXP + lane];
    float nz = noise[row * NEXP + lane];
    float sp = fmaxf(nl, 0.f) + log1pf(expf(-fabsf(nl)));
    float v  = lg + nz * sp;

    float orig = v;
    float work = v;
    bool  sel  = false;
    float myidx = 0.f;
    float m = 0.f, ssum = 0.f;
    float prev = 0.f, minGap = INFINITY;

#pragma unroll
    for (int r = 0; r < TOPK + 1; ++r) {
        float bvv = work;
        int   bi  = lane;
#pragma unroll
        for (int off = 32; off > 0; off >>= 1) {
            float ov = __shfl_xor(bvv, off);
            int   oi = __shfl_xor(bi, off);
            if (ov > bvv || (ov == bvv && oi < bi)) { bvv = ov; bi = oi; }
        }
        if (r > 0) minGap = fminf(minGap, prev - bvv);
        prev = bvv;
        if (r < TOPK) {
            if (r == 0) m = bvv;
            ssum += expf(bvv - m);
            if (lane == bi) { work = -INFINITY; sel = true; }
            if (lane == r)  myidx = (float)bi;
        }
    }

    float p = sel ? expf(orig - m) / ssum : 0.f;
    rout[row * NEXP + lane] = p;
    if (lane < TOPK) idx_out[row * TOPK + lane] = myidx;

    if (lane == 0 && minGap < RISK_TH) {
        int slot = atomicAdd(ctrl, 1);
        if (slot < maxr) list[slot] = rowBase + (int)row;
    }
}

// ---------------- phase C: fp64 recompute of risky rows ----------------
__global__ void init_kernel(int* ctrl) { if (threadIdx.x == 0) ctrl[0] = 0; }

__global__ void pad_kernel(int* ctrl, int* list, int maxr)
{
    int cnt = ctrl[0]; if (cnt > maxr) cnt = maxr;
    int rounded = (cnt + 63) & ~63; if (rounded > maxr) rounded = maxr;
    if (threadIdx.x == 0) { ctrl[1] = rounded; ctrl[2] = cnt; }
    int fill = (cnt > 0) ? list[0] : 0;
    for (int i = cnt + threadIdx.x; i < rounded; i += blockDim.x) list[i] = fill;
}

// fix kernel: P = relu(P + bias) over a 64x64 tile; optionally zero a tile of Z
// (the accumulator buffer the NEXT layer atomically adds into).
__global__ __launch_bounds__(256)
void fixzero_kernel(double* P, const float* __restrict__ bias, int cols,
                    double* Z, int zcols, const int* __restrict__ ctrl)
{
    const int rp = blockIdx.y * 64;
    if (rp >= ctrl[1]) return;
    const int c0 = blockIdx.x * 64;
    if (P && c0 < cols) {
#pragma unroll
        for (int i = 0; i < 8; ++i) {
            int idx = threadIdx.x + i * 256;
            int row = idx >> 5;
            int col = (idx & 31) * 2;
            long o = (long)(rp + row) * cols + c0 + col;
            double2 v = *(double2*)(P + o);
            v.x = fmax(v.x + (double)bias[c0 + col],     0.0);
            v.y = fmax(v.y + (double)bias[c0 + col + 1], 0.0);
            *(double2*)(P + o) = v;
        }
    }
    if (Z && c0 < zcols) {
        const double2 z2 = {0.0, 0.0};
#pragma unroll
        for (int i = 0; i < 8; ++i) {
            int idx = threadIdx.x + i * 256;
            int row = idx >> 5;
            int col = (idx & 31) * 2;
            *(double2*)(Z + (long)(rp + row) * zcols + c0 + col) = z2;
        }
    }
}

// K-split fp64 tile GEMM for risky rows (atomic accumulate, j-major B cols).
#define DBM 64
#define DBN 64
#define DBK 32

__global__ __launch_bounds__(256)
void dgemm_ks(const double* __restrict__ A64, const float* __restrict__ A32,
              const int* __restrict__ rowList,
              const float* __restrict__ B, double* __restrict__ C,
              int N, int K, int kLen, const int* __restrict__ ctrl)
{
    const int mBase = blockIdx.y * DBM;
    if (mBase >= ctrl[1]) return;
    const int kBase = blockIdx.z * kLen;
    const int kEnd  = kBase + kLen;

    __shared__ __align__(16) double As[DBM][DBK + 2];   // m-major, 272B rows
    __shared__ __align__(16) double Bs[DBK][DBN];       // k-major, 512B rows
    __shared__ int rowIdx[DBM];

    const int tid = threadIdx.x;
    const int tx = tid & 15;
    const int ty = tid >> 4;
    const int nBase = blockIdx.x * DBN;

    if (A32 && tid < DBM) rowIdx[tid] = rowList[mBase + tid];
    __syncthreads();

    const int ar = tid >> 4;          // staging row 0..15
    const int ak = (tid & 15) * 2;    // A k-offset (double2)
    const int bc = (tid & 15) * 4;    // B n-offset (float4)

    int rIdx[4];
    if (A32) {
#pragma unroll
        for (int j = 0; j < 4; ++j) rIdx[j] = rowIdx[ar + j * 16];
    }

    double acc[4][4];
#pragma unroll
    for (int i = 0; i < 4; ++i)
#pragma unroll
        for (int j = 0; j < 4; ++j) acc[i][j] = 0.0;

    double2 aReg[4];
    float4  bReg[2];

    auto prefetch = [&](int ktv) {
#pragma unroll
        for (int j = 0; j < 4; ++j) {
            if (A32) {
                const float2 f = *(const float2*)(A32 + (long)rIdx[j] * K + ktv + ak);
                aReg[j].x = (double)f.x; aReg[j].y = (double)f.y;
            } else {
                aReg[j] = *(const double2*)(A64 + (long)(mBase + ar + j * 16) * K + ktv + ak);
            }
        }
#pragma unroll
        for (int j = 0; j < 2; ++j)
            bReg[j] = *(const float4*)(B + (long)(ktv + ar + j * 16) * N + nBase + bc);
    };

    prefetch(kBase);
    int kt = kBase;
    for (;;) {
        // commit staged tile to LDS
#pragma unroll
        for (int j = 0; j < 4; ++j)
            *(double2*)&As[ar + j * 16][ak] = aReg[j];
#pragma unroll
        for (int j = 0; j < 2; ++j) {
            double2 lo, hi;
            lo.x = (double)bReg[j].x; lo.y = (double)bReg[j].y;
            hi.x = (double)bReg[j].z; hi.y = (double)bReg[j].w;
            *(double2*)&Bs[ar + j * 16][bc]     = lo;
            *(double2*)&Bs[ar + j * 16][bc + 2] = hi;
        }
        __syncthreads();

        kt += DBK;
        if (kt < kEnd) prefetch(kt);

#pragma unroll
        for (int k = 0; k < DBK; ++k) {
            double a[4], b[4];
#pragma unroll
            for (int i = 0; i < 4; ++i) a[i] = As[ty * 4 + i][k];   // broadcast b64
#pragma unroll
            for (int j = 0; j < 4; ++j) b[j] = Bs[k][tx + j * 16];  // conflict-free
#pragma unroll
            for (int i = 0; i < 4; ++i)
#pragma unroll
                for (int j = 0; j < 4; ++j)
                    acc[i][j] = fma(a[i], b[j], acc[i][j]);
        }
        __syncthreads();
        if (kt >= kEnd) break;
    }

#pragma unroll
    for (int i = 0; i < 4; ++i) {
        long row = mBase + ty * 4 + i;
#pragma unroll
        for (int j = 0; j < 4; ++j) {
            int n = nBase + tx + j * 16;
#if defined(__HIP_PLATFORM_AMD__)
            unsafeAtomicAdd(&C[row * N + n], acc[i][j]);   // native global_atomic_add_f64
#else
            atomicAdd(&C[row * N + n], acc[i][j]);
#endif
        }
    }
}

__global__ __launch_bounds__(256)
void router_fix_kernel(const double* __restrict__ lgd, const double* __restrict__ nld,
                       const float* __restrict__ b4f, const float* __restrict__ bzf,
                       const float* __restrict__ noise, float* __restrict__ rout,
                       float* __restrict__ idx_out,
                       const int* __restrict__ ctrl, const int* __restrict__ list)
{
    const int wave = threadIdx.x >> 6;
    const int lane = threadIdx.x & 63;
    const int i = blockIdx.x * 4 + wave;
    if (i >= ctrl[2]) return;
    const long row = list[i];

    double lg = lgd[(long)i * NEXP + lane] + (double)b4f[lane];
    double nl = nld[(long)i * NEXP + lane] + (double)bzf[lane];
    double nz = (double)noise[row * NEXP + lane];
    double sp = fmax(nl, 0.0) + log1p(exp(-fabs(nl)));
    double v  = lg + nz * sp;

    double orig = v, work = v;
    bool sel = false;
    float myidx = 0.f;
    double m = 0.0, ssum = 0.0;

#pragma unroll
    for (int r = 0; r < TOPK; ++r) {
        double bvv = work;
        int    bi  = lane;
#pragma unroll
        for (int off = 32; off > 0; off >>= 1) {
            double ov = __shfl_xor(bvv, off);
            int    oi = __shfl_xor(bi, off);
            if (ov > bvv || (ov == bvv && oi < bi)) { bvv = ov; bi = oi; }
        }
        if (r == 0) m = bvv;
        ssum += exp(bvv - m);
        if (lane == bi) { work = -INFINITY; sel = true; }
        if (lane == r)  myidx = (float)bi;
    }

    double p = sel ? exp(orig - m) / ssum : 0.0;
    rout[row * NEXP + lane] = (float)p;
    if (lane < TOPK) idx_out[row * TOPK + lane] = myidx;
}

// ---------------- launch ----------------
extern "C" void kernel_launch(void* const* d_in, const int* in_sizes, int n_in,
                              void* d_out, int out_size, void* d_ws, size_t ws_size,
                              hipStream_t stream)
{
    const float* x     = (const float*)d_in[0];
    const float* noise = (const float*)d_in[1];
    const float* w1 = (const float*)d_in[2];
    const float* b1 = (const float*)d_in[3];
    const float* w2 = (const float*)d_in[4];
    const float* b2 = (const float*)d_in[5];
    const float* wn = (const float*)d_in[6];
    const float* bn = (const float*)d_in[7];
    const float* w3 = (const float*)d_in[8];
    const float* b3 = (const float*)d_in[9];
    const float* w4 = (const float*)d_in[10];
    const float* b4 = (const float*)d_in[11];
    const float* wz = (const float*)d_in[12];
    const float* bz = (const float*)d_in[13];
    float* out = (float*)d_out;

    const int Ntok = in_sizes[0] / IN_DIM;   // 32768

    // --- ws layout: [weight bf16 planes][chunk plane region / fp64 overlay][ctrl+list] ---
    const size_t e1 = (size_t)IN_DIM * H2;   // w1
    const size_t e2 = (size_t)H2 * H2;       // w2
    const size_t en = (size_t)H2 * H2;       // wn
    const size_t e3 = (size_t)H2 * HID;      // w3
    size_t weightBytes = 2 * (e1 + e2 + en + e3) * sizeof(ushort);
    weightBytes = (weightBytes + 255) & ~(size_t)255;

    // per-token region bytes: 4 act planes (4*H2*2B) + u (xp planes / hfin, 4KB) + lg + nl
    const size_t perTok = (size_t)4 * H2 * 2 + (size_t)IN_DIM * 4 + 2 * NEXP * 4;  // 20992
    int chunk = 8192;
    while (chunk > 256) {
        size_t needb = weightBytes + (size_t)chunk * perTok + 65536;
        if (needb <= ws_size) break;
        chunk >>= 1;
    }
    if (chunk > Ntok) chunk = Ntok;

    int MAXR = chunk / 2;
    if (MAXR > 4096) MAXR = 4096;

    ushort* w1Thi = (ushort*)d_ws;
    ushort* w1Tlo = w1Thi + e1;
    ushort* w2Thi = w1Tlo + e1;
    ushort* w2Tlo = w2Thi + e2;
    ushort* wnThi = w2Tlo + e2;
    ushort* wnTlo = wnThi + en;
    ushort* w3Thi = wnTlo + en;
    ushort* w3Tlo = w3Thi + e3;

    char* region = (char*)d_ws + weightBytes;
    const size_t regionBytes = (size_t)chunk * perTok;

    ushort* pAhi = (ushort*)region;
    ushort* pAlo = pAhi + (size_t)chunk * H2;
    ushort* pBhi = pAlo + (size_t)chunk * H2;
    ushort* pBlo = pBhi + (size_t)chunk * H2;
    char*   ureg = (char*)(pBlo + (size_t)chunk * H2);
    ushort* xphi = (ushort*)ureg;                       // xp planes live until gemm1 done
    ushort* xplo = xphi + (size_t)chunk * IN_DIM;
    float*  hfin = (float*)ureg;                        // overlays xp (dead after gemm1)
    float*  lg   = (float*)(ureg + (size_t)chunk * IN_DIM * 4);
    float*  nl   = lg + (size_t)chunk * NEXP;

    double* hA  = (double*)region;                      // fp64 overlay (after fwd pass)
    double* hB  = hA + (size_t)MAXR * H2;
    double* lgd = hB + (size_t)MAXR * H2;
    double* nld = lgd + (size_t)MAXR * NEXP;

    int* ctrl = (int*)(region + regionBytes);
    int* list = ctrl + 16;

    float* ridx = out + (size_t)Ntok * NEXP;

    const dim3 blk(256);
    init_kernel<<<1, 64, 0, stream>>>(ctrl);

    // weight split (every launch: ws is re-poisoned by the harness)
    split_w_kernel<<<dim3(H2 / 64,  IN_DIM / 64), blk, 0, stream>>>(w1, w1Thi, w1Tlo, IN_DIM, H2);
    split_w_kernel<<<dim3(H2 / 64,  H2 / 64),     blk, 0, stream>>>(w2, w2Thi, w2Tlo, H2, H2);
    split_w_kernel<<<dim3(H2 / 64,  H2 / 64),     blk, 0, stream>>>(wn, wnThi, wnTlo, H2, H2);
    split_w_kernel<<<dim3(HID / 64, H2 / 64),     blk, 0, stream>>>(w3, w3Thi, w3Tlo, H2, HID);

    for (int c0 = 0; c0 < Ntok; c0 += chunk) {
        const float* xa = x + (size_t)c0 * IN_DIM;
        split_x_kernel<<<dim3(chunk), blk, 0, stream>>>(xa, xphi, xplo);
        gemm8p_kernel<8, 4><<<dim3(H2 / 256,  chunk / 256), 512, 0, stream>>>(
            xphi, xplo, w1Thi, w1Tlo, b1, nullptr, pAhi, pAlo, H2, IN_DIM);
        gemm8p_kernel<8, 4><<<dim3(H2 / 256,  chunk / 256), 512, 0, stream>>>(
            pAhi, pAlo, w2Thi, w2Tlo, b2, nullptr, pBhi, pBlo, H2, H2);
        gemm8p_kernel<8, 4><<<dim3(H2 / 256,  chunk / 256), 512, 0, stream>>>(
            pBhi, pBlo, wnThi, wnTlo, bn, nullptr, pAhi, pAlo, H2, H2);
        gemm8p_kernel<4, 2><<<dim3(HID / 128, chunk / 256), 512, 0, stream>>>(
            pAhi, pAlo, w3Thi, w3Tlo, b3, hfin, nullptr, nullptr, HID, H2);
        small_gemm_kernel<<<dim3(chunk / SBM), blk, 0, stream>>>(hfin, w4, b4, lg, HID);
        small_gemm_kernel<<<dim3(chunk / SBM), blk, 0, stream>>>(xa,   wz, bz, nl, IN_DIM);
        router_kernel<<<dim3(chunk / 4), blk, 0, stream>>>(lg, nl, noise + (size_t)c0 * NEXP,
                                                           out + (size_t)c0 * NEXP,
                                                           ridx + (size_t)c0 * TOPK, chunk, c0,
                                                           ctrl, list, MAXR);
    }

    pad_kernel<<<1, 256, 0, stream>>>(ctrl, list, MAXR);

    // ---- phase C: K-split atomic-accumulate fp64 chain ----
    const int GY = MAXR / DBM;   // 64
    fixzero_kernel<<<dim3(H2 / 64, GY), blk, 0, stream>>>(nullptr, nullptr, 0, hA, H2, ctrl);
    dgemm_ks<<<dim3(H2 / DBN, GY, 8), blk, 0, stream>>>(nullptr, x, list, w1, hA, H2, IN_DIM, IN_DIM / 8, ctrl);
    fixzero_kernel<<<dim3(H2 / 64, GY), blk, 0, stream>>>(hA, b1, H2, hB, H2, ctrl);
    dgemm_ks<<<dim3(H2 / DBN, GY, 8), blk, 0, stream>>>(hA, nullptr, nullptr, w2, hB, H2, H2, H2 / 8, ctrl);
    fixzero_kernel<<<dim3(H2 / 64, GY), blk, 0, stream>>>(hB, b2, H2, hA, H2, ctrl);
    dgemm_ks<<<dim3(H2 / DBN, GY, 8), blk, 0, stream>>>(hB, nullptr, nullptr, wn, hA, H2, H2, H2 / 8, ctrl);
    fixzero_kernel<<<dim3(H2 / 64, GY), blk, 0, stream>>>(hA, bn, H2, hB, HID, ctrl);
    dgemm_ks<<<dim3(HID / DBN, GY, 8), blk, 0, stream>>>(hA, nullptr, nullptr, w3, hB, HID, H2, H2 / 8, ctrl);
    fixzero_kernel<<<dim3(HID / 64, GY), blk, 0, stream>>>(hB, b3, HID, lgd, NEXP, ctrl);
    fixzero_kernel<<<dim3(1, GY), blk, 0, stream>>>(nullptr, nullptr, 0, nld, NEXP, ctrl);
    dgemm_ks<<<dim3(1, GY, 16), blk, 0, stream>>>(hB, nullptr, nullptr, w4, lgd, NEXP, HID, HID / 16, ctrl);
    dgemm_ks<<<dim3(1, GY, 16), blk, 0, stream>>>(nullptr, x, list, wz, nld, NEXP, IN_DIM, IN_DIM / 16, ctrl);
    router_fix_kernel<<<dim3(MAXR / 4), blk, 0, stream>>>(lgd, nld, b4, bz, noise, out, ridx, ctrl, list);
}

// Round 9
// 2934.317 us; speedup vs baseline: 1.0793x; 1.0793x over previous
//
#include <hip/hip_runtime.h>
#include <math.h>

#define IN_DIM 1024
#define H2     2048
#define HID    1024
#define NEXP   64
#define TOPK   8
#define RISK_TH 1.5e-4f

typedef short  v8s __attribute__((ext_vector_type(8)));   // 8 bf16 (MFMA A/B frag)
typedef float  v4f __attribute__((ext_vector_type(4)));   // 4 f32  (MFMA C/D frag)

// split fp32 -> bf16 hi + bf16 lo (truncation; combined 16-bit mantissa, rel err ~2^-16)
__device__ __forceinline__ void bf16_split(float f, ushort& h, ushort& l) {
    unsigned uh = __float_as_uint(f) & 0xffff0000u;
    h = (ushort)(uh >> 16);
    float r = f - __uint_as_float(uh);
    l = (ushort)(__float_as_uint(r) >> 16);
}

// async global->LDS, 16B per lane. LDS dest is wave-uniform base + lane*16.
__device__ __forceinline__ void gload16(const ushort* g, ushort* l) {
    __builtin_amdgcn_global_load_lds(
        (const __attribute__((address_space(1))) void*)g,
        (__attribute__((address_space(3))) void*)l, 16, 0, 0);
}

// ---------------- weight split+transpose: W[K,N] f32 -> WT_hi/lo[N,K] bf16 ----------------
__global__ __launch_bounds__(256)
void split_w_kernel(const float* __restrict__ W, ushort* __restrict__ hiT,
                    ushort* __restrict__ loT, int K, int N)
{
    __shared__ float T[64][65];
    const int k0 = blockIdx.y * 64, n0 = blockIdx.x * 64;
    const int t = threadIdx.x;
#pragma unroll
    for (int j = 0; j < 4; ++j) {
        int idx = t + j * 256;
        int row = idx >> 4;            // k-local 0..63
        int c4  = (idx & 15) * 4;      // n-local
        float4 f = *(const float4*)(W + (long)(k0 + row) * N + n0 + c4);
        T[row][c4 + 0] = f.x; T[row][c4 + 1] = f.y;
        T[row][c4 + 2] = f.z; T[row][c4 + 3] = f.w;
    }
    __syncthreads();
#pragma unroll
    for (int j = 0; j < 4; ++j) {
        int idx = t + j * 256;
        int nn = idx >> 4;             // n-local 0..63
        int kq = (idx & 15) * 4;       // k-local
        ushort4 h4, l4;
        bf16_split(T[kq + 0][nn], h4.x, l4.x);
        bf16_split(T[kq + 1][nn], h4.y, l4.y);
        bf16_split(T[kq + 2][nn], h4.z, l4.z);
        bf16_split(T[kq + 3][nn], h4.w, l4.w);
        long o = (long)(n0 + nn) * K + k0 + kq;
        *(ushort4*)(hiT + o) = h4;
        *(ushort4*)(loT + o) = l4;
    }
}

// ---------------- x split: fp32 [M,K] -> hi/lo bf16 planes [M,K] ----------------
__global__ __launch_bounds__(256)
void split_x_kernel(const float* __restrict__ X, ushort* __restrict__ hi,
                    ushort* __restrict__ lo)
{
    long i = ((long)blockIdx.x * 256 + threadIdx.x) * 4;
    float4 f = *(const float4*)(X + i);
    ushort4 h4, l4;
    bf16_split(f.x, h4.x, l4.x);
    bf16_split(f.y, h4.y, l4.y);
    bf16_split(f.z, h4.z, l4.z);
    bf16_split(f.w, h4.w, l4.w);
    *(ushort4*)(hi + i) = h4;
    *(ushort4*)(lo + i) = l4;
}

// ---------------- big GEMM: 256xBN bf16x3 MFMA, plane-major MFMA streams ----------------
// A planes [M,K] bf16 (hi/lo), B planes [N,K] bf16 (hi/lo). C = relu(A@B + bias),
// written as fp32 OR as hi/lo planes (for the next layer's A).
// BM=256, BN=NWN*64, BK=32, 8 waves. LDS: 2 buffers x {Ahi,Alo,Bhi,Blo}[rows][32],
// global_load_lds, pre-swizzled per-lane global addresses (SQ_LDS_BANK_CONFLICT=0).
// Sync schedule = best-measured variant (1 s_barrier per tile after vmcnt(0); no
// mid-tile waits — rounds 5-8 tested fenced/unfenced/rhythm/counted-vmcnt, all
// 177-192us, flat -> sync is NOT the limiter).
// NEW (round-8 post-mortem): the MFMA stream itself was chain-serialized — each
// acc's 3 MFMAs are data-dependent (c feeds c), and under 248-VGPR pressure the
// scheduler emits chain-by-chain -> the SIMD sees a dependent MFMA every issue
// slot; with 16x16x32 latency >> 19-cyc issue interval and only 2 waves/SIMD,
// the matrix pipe idles (flat 45-52% MfmaUtil). Fix: PLANE-MAJOR passes — all
// 16 al*bh, then all 16 ah*bl, then all 16 ah*bh. Dependent pairs are now 16
// MFMAs (~300cyc) apart. Each acc still receives its 3 contributions in the
// identical order over ascending K-tiles -> bit-identical output.
// Zigzag A reload: quadrants (0,*) before A1 reload, (1,*) after.
// XCD-aware bijective block swizzle (gridDim.x==8 always; nwg%8==0).
template<int MI, int NWN>
__global__ __launch_bounds__(512, 2)
void gemm8p_kernel(const ushort* __restrict__ gAhi, const ushort* __restrict__ gAlo,
                   const ushort* __restrict__ gBhi, const ushort* __restrict__ gBlo,
                   const float* __restrict__ bias,
                   float* __restrict__ Cf32, ushort* __restrict__ Chi,
                   ushort* __restrict__ Clo, int N, int K)
{
    static_assert(MI == 2 * NWN, "wave grid must tile 256 rows");
    constexpr int BN    = NWN * 64;
    constexpr int ATILE = 256 * 32;          // ushorts per A plane tile (16KB)
    constexpr int BTILE = BN * 32;
    constexpr int BUFU  = 2 * ATILE + 2 * BTILE;
    constexpr int MH    = MI / 2;            // frag-rows per quadrant
    __shared__ __align__(16) ushort lds[2 * BUFU];

    const int tid  = threadIdx.x;
    const int w    = tid >> 6;
    const int lane = tid & 63;
    const int wm   = w / NWN;
    const int wn   = w % NWN;
    const int q    = lane >> 4;
    const int l15  = lane & 15;

    // XCD-aware bijective swizzle (gridDim.x == 8 here).
    const int nwg = (int)(gridDim.x * gridDim.y);
    const int h   = (int)(blockIdx.y * gridDim.x + blockIdx.x);
    const int l   = (h & 7) * (nwg >> 3) + (h >> 3);
    const long bm = (long)(l >> 3) * 256;
    const long bn = (long)(l & 7) * BN;

    const int  e   = lane >> 2;                               // row within slab
    const int  s8  = (((lane & 3) ^ ((lane >> 3) & 3)) * 8);  // swizzled slot (ushorts)
    const int  fragUS = ((q ^ ((l15 >> 1) & 3)) * 8);

    const int NT = K >> 5;

    auto stageA = [&](int ktv, ushort* nb) {
        const long gr = bm + w * 16 + e;
        gload16(gAhi + gr * K + ktv + s8,         nb + w * 512);
        gload16(gAhi + (gr + 128) * K + ktv + s8, nb + 128 * 32 + w * 512);
        gload16(gAlo + gr * K + ktv + s8,         nb + ATILE + w * 512);
        gload16(gAlo + (gr + 128) * K + ktv + s8, nb + ATILE + 128 * 32 + w * 512);
    };
    auto stageB = [&](int ktv, ushort* nb) {
        const long gr = bn + w * 16 + e;
        gload16(gBhi + gr * K + ktv + s8,         nb + 2 * ATILE + w * 512);
        gload16(gBlo + gr * K + ktv + s8,         nb + 2 * ATILE + BTILE + w * 512);
        if constexpr (BN == 256) {
            gload16(gBhi + (gr + 128) * K + ktv + s8, nb + 2 * ATILE + 128 * 32 + w * 512);
            gload16(gBlo + (gr + 128) * K + ktv + s8, nb + 2 * ATILE + BTILE + 128 * 32 + w * 512);
        }
    };

    v4f acc[MI][4];
#pragma unroll
    for (int mi = 0; mi < MI; ++mi)
#pragma unroll
        for (int ni = 0; ni < 4; ++ni)
            acc[mi][ni] = (v4f){0.f, 0.f, 0.f, 0.f};

    // ---- prologue: stage tile 0 into buffer 0 ----
    stageA(0, lds);
    stageB(0, lds);
    asm volatile("s_waitcnt vmcnt(0)" ::: "memory");
    __builtin_amdgcn_s_barrier();
    __builtin_amdgcn_sched_barrier(0);

    // ---- main loop: one K-tile per iteration, single barrier per tile ----
    for (int t = 0; t < NT; ++t) {
        const ushort* cA = lds + (t & 1) * BUFU;
        const ushort* cB = cA + 2 * ATILE;
        ushort* nb = lds + ((t + 1) & 1) * BUFU;
        const bool more = (t + 1 < NT);
        const int  ktn  = (t + 1) << 5;

        v8s ah[MH], al[MH];          // current mh-half A frags (reloaded mid-tile)
        v8s bh0[2], bl0[2];          // nh=0 B frags (held through the tile)
        v8s bh1[2], bl1[2];          // nh=1 B frags (held through the tile)

        // ---- frag reads: A0, B0, B1; stage tile t+1 ----
#pragma unroll
        for (int i = 0; i < MH; ++i) {
            int r = wm * (MI * 16) + i * 16 + l15;
            const ushort* pA = cA + r * 32 + fragUS;
            ah[i] = *(const v8s*)pA;
            al[i] = *(const v8s*)(pA + ATILE);
        }
#pragma unroll
        for (int j = 0; j < 2; ++j) {
            int r = wn * 64 + j * 16 + l15;
            const ushort* pB = cB + r * 32 + fragUS;
            bh0[j] = *(const v8s*)pB;
            bl0[j] = *(const v8s*)(pB + BTILE);
        }
#pragma unroll
        for (int j = 0; j < 2; ++j) {
            int r = wn * 64 + (2 + j) * 16 + l15;
            const ushort* pB = cB + r * 32 + fragUS;
            bh1[j] = *(const v8s*)pB;
            bl1[j] = *(const v8s*)(pB + BTILE);
        }
        if (more) {
            stageA(ktn, nb);
            stageB(ktn, nb);
        }

        // ---- mega-cluster 1: quadrants (0,0)+(0,1), plane-major (3 passes x 16) ----
        __builtin_amdgcn_s_setprio(1);
#pragma unroll
        for (int i = 0; i < MH; ++i)
#pragma unroll
            for (int j = 0; j < 2; ++j) {
                acc[i][j]     = __builtin_amdgcn_mfma_f32_16x16x32_bf16(al[i], bh0[j], acc[i][j],     0, 0, 0);
                acc[i][2 + j] = __builtin_amdgcn_mfma_f32_16x16x32_bf16(al[i], bh1[j], acc[i][2 + j], 0, 0, 0);
            }
#pragma unroll
        for (int i = 0; i < MH; ++i)
#pragma unroll
            for (int j = 0; j < 2; ++j) {
                acc[i][j]     = __builtin_amdgcn_mfma_f32_16x16x32_bf16(ah[i], bl0[j], acc[i][j],     0, 0, 0);
                acc[i][2 + j] = __builtin_amdgcn_mfma_f32_16x16x32_bf16(ah[i], bl1[j], acc[i][2 + j], 0, 0, 0);
            }
#pragma unroll
        for (int i = 0; i < MH; ++i)
#pragma unroll
            for (int j = 0; j < 2; ++j) {
                acc[i][j]     = __builtin_amdgcn_mfma_f32_16x16x32_bf16(ah[i], bh0[j], acc[i][j],     0, 0, 0);
                acc[i][2 + j] = __builtin_amdgcn_mfma_f32_16x16x32_bf16(ah[i], bh1[j], acc[i][2 + j], 0, 0, 0);
            }
        __builtin_amdgcn_s_setprio(0);

        // ---- A1 frag reads (overwrite ah/al; quadrants (0,*) done with A0) ----
#pragma unroll
        for (int i = 0; i < MH; ++i) {
            int r = wm * (MI * 16) + (MH + i) * 16 + l15;
            const ushort* pA = cA + r * 32 + fragUS;
            ah[i] = *(const v8s*)pA;
            al[i] = *(const v8s*)(pA + ATILE);
        }

        // ---- mega-cluster 2: quadrants (1,1)+(1,0), plane-major (3 passes x 16) ----
        __builtin_amdgcn_s_setprio(1);
#pragma unroll
        for (int i = 0; i < MH; ++i)
#pragma unroll
            for (int j = 0; j < 2; ++j) {
                acc[MH + i][2 + j] = __builtin_amdgcn_mfma_f32_16x16x32_bf16(al[i], bh1[j], acc[MH + i][2 + j], 0, 0, 0);
                acc[MH + i][j]     = __builtin_amdgcn_mfma_f32_16x16x32_bf16(al[i], bh0[j], acc[MH + i][j],     0, 0, 0);
            }
#pragma unroll
        for (int i = 0; i < MH; ++i)
#pragma unroll
            for (int j = 0; j < 2; ++j) {
                acc[MH + i][2 + j] = __builtin_amdgcn_mfma_f32_16x16x32_bf16(ah[i], bl1[j], acc[MH + i][2 + j], 0, 0, 0);
                acc[MH + i][j]     = __builtin_amdgcn_mfma_f32_16x16x32_bf16(ah[i], bl0[j], acc[MH + i][j],     0, 0, 0);
            }
#pragma unroll
        for (int i = 0; i < MH; ++i)
#pragma unroll
            for (int j = 0; j < 2; ++j) {
                acc[MH + i][2 + j] = __builtin_amdgcn_mfma_f32_16x16x32_bf16(ah[i], bh1[j], acc[MH + i][2 + j], 0, 0, 0);
                acc[MH + i][j]     = __builtin_amdgcn_mfma_f32_16x16x32_bf16(ah[i], bh0[j], acc[MH + i][j],     0, 0, 0);
            }
        __builtin_amdgcn_s_setprio(0);

        // ---- single end-of-tile sync: DMA of t+1 complete, all waves aligned ----
        asm volatile("s_waitcnt vmcnt(0)" ::: "memory");
        __builtin_amdgcn_s_barrier();
        __builtin_amdgcn_sched_barrier(0);
    }

    // ---- epilogue: bias + relu; fp32 or hi/lo-plane output ----
#pragma unroll
    for (int ni = 0; ni < 4; ++ni) {
        int col = (int)(bn + wn * 64 + ni * 16 + l15);
        float bv = bias[col];
#pragma unroll
        for (int mi = 0; mi < MI; ++mi) {
            long row0 = bm + wm * (MI * 16) + mi * 16 + q * 4;
#pragma unroll
            for (int r = 0; r < 4; ++r) {
                float v = fmaxf(acc[mi][ni][r] + bv, 0.f);
                long o = (row0 + r) * (long)N + col;
                if (Cf32) {
                    Cf32[o] = v;
                } else {
                    ushort hh, ll;
                    bf16_split(v, hh, ll);
                    Chi[o] = hh;
                    Clo[o] = ll;
                }
            }
        }
    }
}

// ---------------- merged small GEMMs (N=64, same K): two problems, blockIdx.y picks ----
#define SBM 64
#define SBK 32
#define SLDA 68

__global__ __launch_bounds__(256, 2)
void small_gemm2_kernel(const float* __restrict__ A0, const float* __restrict__ A1,
                        const float* __restrict__ B0, const float* __restrict__ B1,
                        const float* __restrict__ bias0, const float* __restrict__ bias1,
                        float* __restrict__ C0, float* __restrict__ C1, int K)
{
    const float* A    = blockIdx.y ? A1 : A0;
    const float* B    = blockIdx.y ? B1 : B0;
    const float* bias = blockIdx.y ? bias1 : bias0;
    float*       C    = blockIdx.y ? C1 : C0;

    __shared__ __align__(16) float Hs[SBK][SLDA];
    __shared__ __align__(16) float Ws[SBK][NEXP];
    const int tid = threadIdx.x;
    const int tx = tid & 15;
    const int ty = tid >> 4;
    const long bm = (long)blockIdx.x * SBM;
    const float* Ab = A + bm * K;

    float acc[4][4];
#pragma unroll
    for (int i = 0; i < 4; ++i)
#pragma unroll
        for (int j = 0; j < 4; ++j) acc[i][j] = 0.f;

    float4 aR[2], bR[2];
#pragma unroll
    for (int j = 0; j < 2; ++j) {
        int idx = tid + (j << 8);
        int ar = idx >> 3, ac = (idx & 7) << 2;
        aR[j] = *(const float4*)(Ab + (long)ar * K + ac);
        int br = idx >> 4, bc = (idx & 15) << 2;
        bR[j] = *(const float4*)(B + (long)br * NEXP + bc);
    }

    int kt = 0;
    for (;;) {
#pragma unroll
        for (int j = 0; j < 2; ++j) {
            int idx = tid + (j << 8);
            int ar = idx >> 3, ac = (idx & 7) << 2;
            Hs[ac + 0][ar] = aR[j].x;
            Hs[ac + 1][ar] = aR[j].y;
            Hs[ac + 2][ar] = aR[j].z;
            Hs[ac + 3][ar] = aR[j].w;
            int br = idx >> 4, bc = (idx & 15) << 2;
            *(float4*)&Ws[br][bc] = bR[j];
        }
        __syncthreads();

        kt += SBK;
        if (kt < K) {
#pragma unroll
            for (int j = 0; j < 2; ++j) {
                int idx = tid + (j << 8);
                int ar = idx >> 3, ac = (idx & 7) << 2;
                aR[j] = *(const float4*)(Ab + (long)ar * K + kt + ac);
                int br = idx >> 4, bc = (idx & 15) << 2;
                bR[j] = *(const float4*)(B + (long)(kt + br) * NEXP + bc);
            }
        }

#pragma unroll
        for (int k = 0; k < SBK; ++k) {
            float a[4], b[4];
            *(float4*)&a[0] = *(const float4*)&Hs[k][ty * 4];
            *(float4*)&b[0] = *(const float4*)&Ws[k][tx * 4];
#pragma unroll
            for (int i = 0; i < 4; ++i)
#pragma unroll
                for (int j = 0; j < 4; ++j)
                    acc[i][j] = fmaf(a[i], b[j], acc[i][j]);
        }
        __syncthreads();
        if (kt >= K) break;
    }

    float bv[4];
#pragma unroll
    for (int j = 0; j < 4; ++j) bv[j] = bias[tx * 4 + j];
#pragma unroll
    for (int i = 0; i < 4; ++i) {
        long row = bm + ty * 4 + i;
        float o[4];
#pragma unroll
        for (int j = 0; j < 4; ++j) o[j] = acc[i][j] + bv[j];
        *(float4*)(C + row * NEXP + tx * 4) = *(const float4*)&o[0];
    }
}

// ---------------- router (fp32) + risky-row detection ----------------
__global__ __launch_bounds__(256)
void router_kernel(const float* __restrict__ logits, const float* __restrict__ nlog,
                   const float* __restrict__ noise, float* __restrict__ rout,
                   float* __restrict__ idx_out, int rows, int rowBase,
                   int* __restrict__ ctrl, int* __restrict__ list, int maxr)
{
    const int wave = threadIdx.x >> 6;
    const int lane = threadIdx.x & 63;
    const long row = (long)blockIdx.x * 4 + wave;
    if (row >= rows) return;

    float lg = logits[row * NEXP + lane];
    float nl = nlog[row * NEXP + lane];
    float nz = noise[row * NEXP + lane];
    float sp = fmaxf(nl, 0.f) + log1pf(expf(-fabsf(nl)));
    float v  = lg + nz * sp;

    float orig = v;
    float work = v;
    bool  sel  = false;
    float myidx = 0.f;
    float m = 0.f, ssum = 0.f;
    float prev = 0.f, minGap = INFINITY;

#pragma unroll
    for (int r = 0; r < TOPK + 1; ++r) {
        float bvv = work;
        int   bi  = lane;
#pragma unroll
        for (int off = 32; off > 0; off >>= 1) {
            float ov = __shfl_xor(bvv, off);
            int   oi = __shfl_xor(bi, off);
            if (ov > bvv || (ov == bvv && oi < bi)) { bvv = ov; bi = oi; }
        }
        if (r > 0) minGap = fminf(minGap, prev - bvv);
        prev = bvv;
        if (r < TOPK) {
            if (r == 0) m = bvv;
            ssum += expf(bvv - m);
            if (lane == bi) { work = -INFINITY; sel = true; }
            if (lane == r)  myidx = (float)bi;
        }
    }

    float p = sel ? expf(orig - m) / ssum : 0.f;
    rout[row * NEXP + lane] = p;
    if (lane < TOPK) idx_out[row * TOPK + lane] = myidx;

    if (lane == 0 && minGap < RISK_TH) {
        int slot = atomicAdd(ctrl, 1);
        if (slot < maxr) list[slot] = rowBase + (int)row;
    }
}

// ---------------- phase C: fp64 recompute of risky rows ----------------
__global__ void init_kernel(int* ctrl) { if (threadIdx.x == 0) ctrl[0] = 0; }

__global__ void pad_kernel(int* ctrl, int* list, int maxr)
{
    int cnt = ctrl[0]; if (cnt > maxr) cnt = maxr;
    int rounded = (cnt + 63) & ~63; if (rounded > maxr) rounded = maxr;
    if (threadIdx.x == 0) { ctrl[1] = rounded; ctrl[2] = cnt; }
    int fill = (cnt > 0) ? list[0] : 0;
    for (int i = cnt + threadIdx.x; i < rounded; i += blockDim.x) list[i] = fill;
}

// fix kernel: P = relu(P + bias) over a 64x64 tile; optionally zero a tile of Z.
__global__ __launch_bounds__(256)
void fixzero_kernel(double* P, const float* __restrict__ bias, int cols,
                    double* Z, int zcols, const int* __restrict__ ctrl)
{
    const int rp = blockIdx.y * 64;
    if (rp >= ctrl[1]) return;
    const int c0 = blockIdx.x * 64;
    if (P && c0 < cols) {
#pragma unroll
        for (int i = 0; i < 8; ++i) {
            int idx = threadIdx.x + i * 256;
            int row = idx >> 5;
            int col = (idx & 31) * 2;
            long o = (long)(rp + row) * cols + c0 + col;
            double2 v = *(double2*)(P + o);
            v.x = fmax(v.x + (double)bias[c0 + col],     0.0);
            v.y = fmax(v.y + (double)bias[c0 + col + 1], 0.0);
            *(double2*)(P + o) = v;
        }
    }
    if (Z && c0 < zcols) {
        const double2 z2 = {0.0, 0.0};
#pragma unroll
        for (int i = 0; i < 8; ++i) {
            int idx = threadIdx.x + i * 256;
            int row = idx >> 5;
            int col = (idx & 31) * 2;
            *(double2*)(Z + (long)(rp + row) * zcols + c0 + col) = z2;
        }
    }
}

// K-split fp64 tile GEMM for risky rows (atomic accumulate, j-major B cols).
#define DBM 64
#define DBN 64
#define DBK 32

__global__ __launch_bounds__(256)
void dgemm_ks(const double* __restrict__ A64, const float* __restrict__ A32,
              const int* __restrict__ rowList,
              const float* __restrict__ B, double* __restrict__ C,
              int N, int K, int kLen, const int* __restrict__ ctrl)
{
    const int mBase = blockIdx.y * DBM;
    if (mBase >= ctrl[1]) return;
    const int kBase = blockIdx.z * kLen;
    const int kEnd  = kBase + kLen;

    __shared__ __align__(16) double As[DBM][DBK + 2];   // m-major, 272B rows
    __shared__ __align__(16) double Bs[DBK][DBN];       // k-major, 512B rows
    __shared__ int rowIdx[DBM];

    const int tid = threadIdx.x;
    const int tx = tid & 15;
    const int ty = tid >> 4;
    const int nBase = blockIdx.x * DBN;

    if (A32 && tid < DBM) rowIdx[tid] = rowList[mBase + tid];
    __syncthreads();

    const int ar = tid >> 4;          // staging row 0..15
    const int ak = (tid & 15) * 2;    // A k-offset (double2)
    const int bc = (tid & 15) * 4;    // B n-offset (float4)

    int rIdx[4];
    if (A32) {
#pragma unroll
        for (int j = 0; j < 4; ++j) rIdx[j] = rowIdx[ar + j * 16];
    }

    double acc[4][4];
#pragma unroll
    for (int i = 0; i < 4; ++i)
#pragma unroll
        for (int j = 0; j < 4; ++j) acc[i][j] = 0.0;

    double2 aReg[4];
    float4  bReg[2];

    auto prefetch = [&](int ktv) {
#pragma unroll
        for (int j = 0; j < 4; ++j) {
            if (A32) {
                const float2 f = *(const float2*)(A32 + (long)rIdx[j] * K + ktv + ak);
                aReg[j].x = (double)f.x; aReg[j].y = (double)f.y;
            } else {
                aReg[j] = *(const double2*)(A64 + (long)(mBase + ar + j * 16) * K + ktv + ak);
            }
        }
#pragma unroll
        for (int j = 0; j < 2; ++j)
            bReg[j] = *(const float4*)(B + (long)(ktv + ar + j * 16) * N + nBase + bc);
    };

    prefetch(kBase);
    int kt = kBase;
    for (;;) {
        // commit staged tile to LDS
#pragma unroll
        for (int j = 0; j < 4; ++j)
            *(double2*)&As[ar + j * 16][ak] = aReg[j];
#pragma unroll
        for (int j = 0; j < 2; ++j) {
            double2 lo, hi;
            lo.x = (double)bReg[j].x; lo.y = (double)bReg[j].y;
            hi.x = (double)bReg[j].z; hi.y = (double)bReg[j].w;
            *(double2*)&Bs[ar + j * 16][bc]     = lo;
            *(double2*)&Bs[ar + j * 16][bc + 2] = hi;
        }
        __syncthreads();

        kt += DBK;
        if (kt < kEnd) prefetch(kt);

#pragma unroll
        for (int k = 0; k < DBK; ++k) {
            double a[4], b[4];
#pragma unroll
            for (int i = 0; i < 4; ++i) a[i] = As[ty * 4 + i][k];   // broadcast b64
#pragma unroll
            for (int j = 0; j < 4; ++j) b[j] = Bs[k][tx + j * 16];  // conflict-free
#pragma unroll
            for (int i = 0; i < 4; ++i)
#pragma unroll
                for (int j = 0; j < 4; ++j)
                    acc[i][j] = fma(a[i], b[j], acc[i][j]);
        }
        __syncthreads();
        if (kt >= kEnd) break;
    }

#pragma unroll
    for (int i = 0; i < 4; ++i) {
        long row = mBase + ty * 4 + i;
#pragma unroll
        for (int j = 0; j < 4; ++j) {
            int n = nBase + tx + j * 16;
#if defined(__HIP_PLATFORM_AMD__)
            unsafeAtomicAdd(&C[row * N + n], acc[i][j]);   // native global_atomic_add_f64
#else
            atomicAdd(&C[row * N + n], acc[i][j]);
#endif
        }
    }
}

__global__ __launch_bounds__(256)
void router_fix_kernel(const double* __restrict__ lgd, const double* __restrict__ nld,
                       const float* __restrict__ b4f, const float* __restrict__ bzf,
                       const float* __restrict__ noise, float* __restrict__ rout,
                       float* __restrict__ idx_out,
                       const int* __restrict__ ctrl, const int* __restrict__ list)
{
    const int wave = threadIdx.x >> 6;
    const int lane = threadIdx.x & 63;
    const int i = blockIdx.x * 4 + wave;
    if (i >= ctrl[2]) return;
    const long row = list[i];

    double lg = lgd[(long)i * NEXP + lane] + (double)b4f[lane];
    double nl = nld[(long)i * NEXP + lane] + (double)bzf[lane];
    double nz = (double)noise[row * NEXP + lane];
    double sp = fmax(nl, 0.0) + log1p(exp(-fabs(nl)));
    double v  = lg + nz * sp;

    double orig = v, work = v;
    bool sel = false;
    float myidx = 0.f;
    double m = 0.0, ssum = 0.0;

#pragma unroll
    for (int r = 0; r < TOPK; ++r) {
        double bvv = work;
        int    bi  = lane;
#pragma unroll
        for (int off = 32; off > 0; off >>= 1) {
            double ov = __shfl_xor(bvv, off);
            int    oi = __shfl_xor(bi, off);
            if (ov > bvv || (ov == bvv && oi < bi)) { bvv = ov; bi = oi; }
        }
        if (r == 0) m = bvv;
        ssum += exp(bvv - m);
        if (lane == bi) { work = -INFINITY; sel = true; }
        if (lane == r)  myidx = (float)bi;
    }

    double p = sel ? exp(orig - m) / ssum : 0.0;
    rout[row * NEXP + lane] = (float)p;
    if (lane < TOPK) idx_out[row * TOPK + lane] = myidx;
}

// ---------------- launch ----------------
extern "C" void kernel_launch(void* const* d_in, const int* in_sizes, int n_in,
                              void* d_out, int out_size, void* d_ws, size_t ws_size,
                              hipStream_t stream)
{
    const float* x     = (const float*)d_in[0];
    const float* noise = (const float*)d_in[1];
    const float* w1 = (const float*)d_in[2];
    const float* b1 = (const float*)d_in[3];
    const float* w2 = (const float*)d_in[4];
    const float* b2 = (const float*)d_in[5];
    const float* wn = (const float*)d_in[6];
    const float* bn = (const float*)d_in[7];
    const float* w3 = (const float*)d_in[8];
    const float* b3 = (const float*)d_in[9];
    const float* w4 = (const float*)d_in[10];
    const float* b4 = (const float*)d_in[11];
    const float* wz = (const float*)d_in[12];
    const float* bz = (const float*)d_in[13];
    float* out = (float*)d_out;

    const int Ntok = in_sizes[0] / IN_DIM;   // 32768

    // --- ws layout: [weight bf16 planes][chunk plane region / fp64 overlay][ctrl+list] ---
    const size_t e1 = (size_t)IN_DIM * H2;   // w1
    const size_t e2 = (size_t)H2 * H2;       // w2
    const size_t en = (size_t)H2 * H2;       // wn
    const size_t e3 = (size_t)H2 * HID;      // w3
    size_t weightBytes = 2 * (e1 + e2 + en + e3) * sizeof(ushort);
    weightBytes = (weightBytes + 255) & ~(size_t)255;

    // per-token region bytes: 4 act planes (4*H2*2B) + u (xp planes / hfin, 4KB) + lg + nl
    const size_t perTok = (size_t)4 * H2 * 2 + (size_t)IN_DIM * 4 + 2 * NEXP * 4;  // 20992
    int chunk = 8192;
    while (chunk > 256) {
        size_t needb = weightBytes + (size_t)chunk * perTok + 65536;
        if (needb <= ws_size) break;
        chunk >>= 1;
    }
    if (chunk > Ntok) chunk = Ntok;

    int MAXR = chunk / 2;
    if (MAXR > 4096) MAXR = 4096;

    ushort* w1Thi = (ushort*)d_ws;
    ushort* w1Tlo = w1Thi + e1;
    ushort* w2Thi = w1Tlo + e1;
    ushort* w2Tlo = w2Thi + e2;
    ushort* wnThi = w2Tlo + e2;
    ushort* wnTlo = wnThi + en;
    ushort* w3Thi = wnTlo + en;
    ushort* w3Tlo = w3Thi + e3;

    char* region = (char*)d_ws + weightBytes;
    const size_t regionBytes = (size_t)chunk * perTok;

    ushort* pAhi = (ushort*)region;
    ushort* pAlo = pAhi + (size_t)chunk * H2;
    ushort* pBhi = pAlo + (size_t)chunk * H2;
    ushort* pBlo = pBhi + (size_t)chunk * H2;
    char*   ureg = (char*)(pBlo + (size_t)chunk * H2);
    ushort* xphi = (ushort*)ureg;                       // xp planes live until gemm1 done
    ushort* xplo = xphi + (size_t)chunk * IN_DIM;
    float*  hfin = (float*)ureg;                        // overlays xp (dead after gemm1)
    float*  lg   = (float*)(ureg + (size_t)chunk * IN_DIM * 4);
    float*  nl   = lg + (size_t)chunk * NEXP;

    double* hA  = (double*)region;                      // fp64 overlay (after fwd pass)
    double* hB  = hA + (size_t)MAXR * H2;
    double* lgd = hB + (size_t)MAXR * H2;
    double* nld = lgd + (size_t)MAXR * NEXP;

    int* ctrl = (int*)(region + regionBytes);
    int* list = ctrl + 16;

    float* ridx = out + (size_t)Ntok * NEXP;

    const dim3 blk(256);
    init_kernel<<<1, 64, 0, stream>>>(ctrl);

    // weight split (every launch: ws is re-poisoned by the harness)
    split_w_kernel<<<dim3(H2 / 64,  IN_DIM / 64), blk, 0, stream>>>(w1, w1Thi, w1Tlo, IN_DIM, H2);
    split_w_kernel<<<dim3(H2 / 64,  H2 / 64),     blk, 0, stream>>>(w2, w2Thi, w2Tlo, H2, H2);
    split_w_kernel<<<dim3(H2 / 64,  H2 / 64),     blk, 0, stream>>>(wn, wnThi, wnTlo, H2, H2);
    split_w_kernel<<<dim3(HID / 64, H2 / 64),     blk, 0, stream>>>(w3, w3Thi, w3Tlo, H2, HID);

    for (int c0 = 0; c0 < Ntok; c0 += chunk) {
        const float* xa = x + (size_t)c0 * IN_DIM;
        split_x_kernel<<<dim3(chunk), blk, 0, stream>>>(xa, xphi, xplo);
        gemm8p_kernel<8, 4><<<dim3(H2 / 256,  chunk / 256), 512, 0, stream>>>(
            xphi, xplo, w1Thi, w1Tlo, b1, nullptr, pAhi, pAlo, H2, IN_DIM);
        gemm8p_kernel<8, 4><<<dim3(H2 / 256,  chunk / 256), 512, 0, stream>>>(
            pAhi, pAlo, w2Thi, w2Tlo, b2, nullptr, pBhi, pBlo, H2, H2);
        gemm8p_kernel<8, 4><<<dim3(H2 / 256,  chunk / 256), 512, 0, stream>>>(
            pBhi, pBlo, wnThi, wnTlo, bn, nullptr, pAhi, pAlo, H2, H2);
        gemm8p_kernel<4, 2><<<dim3(HID / 128, chunk / 256), 512, 0, stream>>>(
            pAhi, pAlo, w3Thi, w3Tlo, b3, hfin, nullptr, nullptr, HID, H2);
        small_gemm2_kernel<<<dim3(chunk / SBM, 2), blk, 0, stream>>>(
            hfin, xa, w4, wz, b4, bz, lg, nl, IN_DIM);
        router_kernel<<<dim3(chunk / 4), blk, 0, stream>>>(lg, nl, noise + (size_t)c0 * NEXP,
                                                           out + (size_t)c0 * NEXP,
                                                           ridx + (size_t)c0 * TOPK, chunk, c0,
                                                           ctrl, list, MAXR);
    }

    pad_kernel<<<1, 256, 0, stream>>>(ctrl, list, MAXR);

    // ---- phase C: K-split atomic-accumulate fp64 chain ----
    const int GY = MAXR / DBM;   // 64
    fixzero_kernel<<<dim3(H2 / 64, GY), blk, 0, stream>>>(nullptr, nullptr, 0, hA, H2, ctrl);
    dgemm_ks<<<dim3(H2 / DBN, GY, 8), blk, 0, stream>>>(nullptr, x, list, w1, hA, H2, IN_DIM, IN_DIM / 8, ctrl);
    fixzero_kernel<<<dim3(H2 / 64, GY), blk, 0, stream>>>(hA, b1, H2, hB, H2, ctrl);
    dgemm_ks<<<dim3(H2 / DBN, GY, 8), blk, 0, stream>>>(hA, nullptr, nullptr, w2, hB, H2, H2, H2 / 8, ctrl);
    fixzero_kernel<<<dim3(H2 / 64, GY), blk, 0, stream>>>(hB, b2, H2, hA, H2, ctrl);
    dgemm_ks<<<dim3(H2 / DBN, GY, 8), blk, 0, stream>>>(hB, nullptr, nullptr, wn, hA, H2, H2, H2 / 8, ctrl);
    fixzero_kernel<<<dim3(H2 / 64, GY), blk, 0, stream>>>(hA, bn, H2, hB, HID, ctrl);
    dgemm_ks<<<dim3(HID / DBN, GY, 8), blk, 0, stream>>>(hA, nullptr, nullptr, w3, hB, HID, H2, H2 / 8, ctrl);
    fixzero_kernel<<<dim3(HID / 64, GY), blk, 0, stream>>>(hB, b3, HID, lgd, NEXP, ctrl);
    fixzero_kernel<<<dim3(1, GY), blk, 0, stream>>>(nullptr, nullptr, 0, nld, NEXP, ctrl);
    dgemm_ks<<<dim3(1, GY, 16), blk, 0, stream>>>(hB, nullptr, nullptr, w4, lgd, NEXP, HID, HID / 16, ctrl);
    dgemm_ks<<<dim3(1, GY, 16), blk, 0, stream>>>(nullptr, x, list, wz, nld, NEXP, IN_DIM, IN_DIM / 16, ctrl);
    router_fix_kernel<<<dim3(MAXR / 4), blk, 0, stream>>>(lgd, nld, b4, bz, noise, out, ridx, ctrl, list);
}